// Round 1
// baseline (11401.238 us; speedup 1.0000x reference)
//
#include <hip/hip_runtime.h>
#include <hip/hip_bf16.h>
#include <cstddef>

#define B_   16
#define N_   1024
#define H_   2
#define D_   128
#define A_   256
#define FFN_ 1024
#define M_   (B_ * N_)   // 16384 rows
#define EPS_ 1e-5f

// ---------------------------------------------------------------------------
// Tiled fp32 GEMM: C[M,Nout] = A[M,K] @ W[K,Nout] + bias, optional ReLU.
// HEADS=true writes output in [B,H,N,D] layout (head-transposed) for attention.
// 64x64 tile, 256 threads, 4x4 accumulators per thread, BK=16.
// ---------------------------------------------------------------------------
#define BM 64
#define BN 64
#define BK 16

template <bool RELU, bool HEADS>
__global__ __launch_bounds__(256) void gemm_kernel(
    const float* __restrict__ Ain, const float* __restrict__ W,
    const float* __restrict__ bias, float* __restrict__ C,
    int M, int K, int Nout)
{
    __shared__ float sA[BM][BK + 1];
    __shared__ float sB[BK][BN + 1];

    const int tid = threadIdx.x;
    const int tx = tid & 15, ty = tid >> 4;
    const int m0 = blockIdx.x * BM;
    const int n0 = blockIdx.y * BN;

    float acc[4][4] = {};

    for (int k0 = 0; k0 < K; k0 += BK) {
        // A tile 64x16: thread loads one float4
        {
            int r = tid >> 2, c = (tid & 3) * 4;
            float4 va = *reinterpret_cast<const float4*>(
                Ain + (size_t)(m0 + r) * K + k0 + c);
            sA[r][c + 0] = va.x; sA[r][c + 1] = va.y;
            sA[r][c + 2] = va.z; sA[r][c + 3] = va.w;
        }
        // B tile 16x64: thread loads one float4
        {
            int r = tid >> 4, c = (tid & 15) * 4;
            float4 vb = *reinterpret_cast<const float4*>(
                W + (size_t)(k0 + r) * Nout + n0 + c);
            sB[r][c + 0] = vb.x; sB[r][c + 1] = vb.y;
            sB[r][c + 2] = vb.z; sB[r][c + 3] = vb.w;
        }
        __syncthreads();
#pragma unroll
        for (int kk = 0; kk < BK; ++kk) {
            float a[4], b[4];
#pragma unroll
            for (int i = 0; i < 4; ++i) a[i] = sA[ty * 4 + i][kk];
#pragma unroll
            for (int j = 0; j < 4; ++j) b[j] = sB[kk][tx * 4 + j];
#pragma unroll
            for (int i = 0; i < 4; ++i)
#pragma unroll
                for (int j = 0; j < 4; ++j) acc[i][j] += a[i] * b[j];
        }
        __syncthreads();
    }

#pragma unroll
    for (int i = 0; i < 4; ++i) {
        int m = m0 + ty * 4 + i;
#pragma unroll
        for (int j = 0; j < 4; ++j) {
            int n = n0 + tx * 4 + j;
            float v = acc[i][j] + bias[n];
            if (RELU) v = fmaxf(v, 0.f);
            if (HEADS) {
                // m = b*N + n_pos ; n = h*D + d  ->  [(b*H + h)*N + n_pos]*D + d
                int bb = m >> 10, np = m & (N_ - 1);
                int hh = n >> 7,  dd = n & (D_ - 1);
                C[(size_t)(((bb * H_ + hh) * N_ + np)) * D_ + dd] = v;
            } else {
                C[(size_t)m * Nout + n] = v;
            }
        }
    }
}

// ---------------------------------------------------------------------------
// Attention: one block = (bh, 16 query rows). Scores kept in LDS (padded),
// softmax via 16-lane shfl groups, PV with V tiles staged in LDS.
// q,k,v layout: [B*H, N, D]. Output written back to [B, N, A] layout.
// ---------------------------------------------------------------------------
#define TQ 16
#define TK 32

__global__ __launch_bounds__(256) void attn_kernel(
    const float* __restrict__ q, const float* __restrict__ k,
    const float* __restrict__ v, float* __restrict__ out)
{
    __shared__ float sQ[TQ * D_];            //  8 KB
    __shared__ float sS[TQ * (N_ + 1)];      // 64.1 KB (pad stride 1025)
    __shared__ float sKV[TK * (D_ + 1)];     // 16.1 KB (pad stride 129)
    __shared__ float sSum[TQ];

    const int tid = threadIdx.x;
    const int bh  = blockIdx.x;          // 0..31
    const int q0  = blockIdx.y * TQ;

    const float* qb = q + ((size_t)bh * N_ + q0) * D_;
    const float* kb = k + (size_t)bh * N_ * D_;
    const float* vb = v + (size_t)bh * N_ * D_;
    const float scale = 0.08838834764831845f;  // 1/sqrt(128)

    for (int idx = tid; idx < TQ * D_; idx += 256) sQ[idx] = qb[idx];
    __syncthreads();

    // ---- scores ----
    for (int kt = 0; kt < N_ / TK; ++kt) {
        for (int idx = tid; idx < TK * D_; idx += 256) {
            int r = idx >> 7, c = idx & (D_ - 1);
            sKV[r * (D_ + 1) + c] = kb[(size_t)(kt * TK + r) * D_ + c];
        }
        __syncthreads();
#pragma unroll
        for (int p = 0; p < 2; ++p) {
            int pr = tid + p * 256;          // 0..511
            int qq = pr >> 5, kk = pr & 31;
            float s = 0.f;
#pragma unroll 8
            for (int d = 0; d < D_; ++d)
                s += sQ[qq * D_ + d] * sKV[kk * (D_ + 1) + d];
            sS[qq * (N_ + 1) + kt * TK + kk] = s * scale;
        }
        __syncthreads();
    }

    // ---- softmax (16 lanes per row) ----
    {
        int qq = tid >> 4, i = tid & 15;
        float m = -1e30f;
        for (int j = i; j < N_; j += 16) m = fmaxf(m, sS[qq * (N_ + 1) + j]);
#pragma unroll
        for (int o = 8; o > 0; o >>= 1) m = fmaxf(m, __shfl_xor(m, o, 16));
        float sum = 0.f;
        for (int j = i; j < N_; j += 16) {
            float p = __expf(sS[qq * (N_ + 1) + j] - m);
            sS[qq * (N_ + 1) + j] = p;
            sum += p;
        }
#pragma unroll
        for (int o = 8; o > 0; o >>= 1) sum += __shfl_xor(sum, o, 16);
        if (i == 0) sSum[qq] = sum;
    }
    __syncthreads();

    // ---- PV ----
    const int qq = tid >> 4, i = tid & 15, d0 = i * 8;
    float acc[8] = {};
    for (int vt = 0; vt < N_ / TK; ++vt) {
        for (int idx = tid; idx < TK * D_; idx += 256) {
            int r = idx >> 7, c = idx & (D_ - 1);
            sKV[r * (D_ + 1) + c] = vb[(size_t)(vt * TK + r) * D_ + c];
        }
        __syncthreads();
#pragma unroll 4
        for (int kk = 0; kk < TK; ++kk) {
            float p = sS[qq * (N_ + 1) + vt * TK + kk];
#pragma unroll
            for (int dd = 0; dd < 8; ++dd)
                acc[dd] += p * sKV[kk * (D_ + 1) + d0 + dd];
        }
        __syncthreads();
    }
    const float inv = 1.0f / sSum[qq];
    const int bb = bh >> 1, hh = bh & 1;
    float* ob = out + ((size_t)(bb * N_ + q0 + qq)) * A_ + hh * D_ + d0;
#pragma unroll
    for (int dd = 0; dd < 8; ++dd) ob[dd] = acc[dd] * inv;
}

// ---------------------------------------------------------------------------
// Fused FFN (in place): x <- relu(relu(x@W1+b1)@W2+b2), TR rows per block.
// ---------------------------------------------------------------------------
template <int TR>
__global__ __launch_bounds__(256) void ffn_kernel(
    float* __restrict__ x, const float* __restrict__ W1,
    const float* __restrict__ b1, const float* __restrict__ W2,
    const float* __restrict__ b2)
{
    __shared__ float sx[TR][A_];
    __shared__ float sh[TR][FFN_];
    const int row0 = blockIdx.x * TR;
    const int tid = threadIdx.x;

    for (int idx = tid; idx < TR * A_; idx += 256)
        sx[idx >> 8][idx & (A_ - 1)] = x[(size_t)row0 * A_ + idx];
    __syncthreads();

    for (int jj = 0; jj < FFN_ / 256; ++jj) {
        int j = jj * 256 + tid;
        float acc[TR];
#pragma unroll
        for (int r = 0; r < TR; ++r) acc[r] = b1[j];
        for (int kk = 0; kk < A_; ++kk) {
            float w = W1[(size_t)kk * FFN_ + j];
#pragma unroll
            for (int r = 0; r < TR; ++r) acc[r] += sx[r][kk] * w;
        }
#pragma unroll
        for (int r = 0; r < TR; ++r) sh[r][j] = fmaxf(acc[r], 0.f);
    }
    __syncthreads();
    {
        float acc[TR];
#pragma unroll
        for (int r = 0; r < TR; ++r) acc[r] = b2[tid];
        for (int kk = 0; kk < FFN_; ++kk) {
            float w = W2[(size_t)kk * A_ + tid];
#pragma unroll
            for (int r = 0; r < TR; ++r) acc[r] += sh[r][kk] * w;
        }
#pragma unroll
        for (int r = 0; r < TR; ++r)
            x[(size_t)(row0 + r) * A_ + tid] = fmaxf(acc[r], 0.f);
    }
}

// ---------------------------------------------------------------------------
// step = LayerNorm(roll + prev) * g + b  — one block per row (A=256 threads)
// ---------------------------------------------------------------------------
__global__ __launch_bounds__(256) void add_ln_kernel(
    const float* __restrict__ roll, const float* __restrict__ prev,
    const float* __restrict__ g, const float* __restrict__ bta,
    float* __restrict__ out)
{
    const int row = blockIdx.x, tid = threadIdx.x;
    float v = roll[(size_t)row * A_ + tid] + prev[(size_t)row * A_ + tid];
    float s = v, s2 = v * v;
#pragma unroll
    for (int o = 32; o > 0; o >>= 1) {
        s  += __shfl_down(s, o, 64);
        s2 += __shfl_down(s2, o, 64);
    }
    __shared__ float ps[4], ps2[4];
    __shared__ float mu_s, rsig_s;
    const int wid = tid >> 6, lane = tid & 63;
    if (lane == 0) { ps[wid] = s; ps2[wid] = s2; }
    __syncthreads();
    if (tid == 0) {
        float S  = ps[0] + ps[1] + ps[2] + ps[3];
        float S2 = ps2[0] + ps2[1] + ps2[2] + ps2[3];
        float mu = S / A_;
        float var = S2 / A_ - mu * mu;
        mu_s = mu;
        rsig_s = rsqrtf(var + EPS_);
    }
    __syncthreads();
    out[(size_t)row * A_ + tid] = (v - mu_s) * rsig_s * g[tid] + bta[tid];
}

// ---------------------------------------------------------------------------
// Pool: partial sums over 32-row chunks of entity encodings
// ---------------------------------------------------------------------------
__global__ __launch_bounds__(256) void pool_kernel(
    const float* __restrict__ ent, float* __restrict__ part)
{
    const int b = blockIdx.x, s = blockIdx.y, a = threadIdx.x;
    float acc = 0.f;
    for (int n = s * 32; n < s * 32 + 32; ++n)
        acc += ent[((size_t)b * N_ + n) * A_ + a];
    part[((size_t)b * 32 + s) * A_ + a] = acc;
}

// ---------------------------------------------------------------------------
// Final: pooled = mean -> relu(pooled @ We + be), fp32 output
// ---------------------------------------------------------------------------
__global__ __launch_bounds__(256) void final_kernel(
    const float* __restrict__ part, const float* __restrict__ We,
    const float* __restrict__ be, float* __restrict__ out)
{
    __shared__ float sp[A_];
    const int b = blockIdx.x, tid = threadIdx.x;
    float s = 0.f;
    for (int j = 0; j < 32; ++j) s += part[((size_t)b * 32 + j) * A_ + tid];
    sp[tid] = s * (1.0f / N_);
    __syncthreads();
    float acc = be[tid];
    for (int kk = 0; kk < A_; ++kk) acc += sp[kk] * We[(size_t)kk * A_ + tid];
    out[b * A_ + tid] = fmaxf(acc, 0.f);
}

// ---------------------------------------------------------------------------
extern "C" void kernel_launch(void* const* d_in, const int* in_sizes, int n_in,
                              void* d_out, int out_size, void* d_ws, size_t ws_size,
                              hipStream_t stream)
{
    const float* X    = (const float*)d_in[0];
    const float* Wq   = (const float*)d_in[1];
    const float* bq   = (const float*)d_in[2];
    const float* Wk   = (const float*)d_in[3];
    const float* bk   = (const float*)d_in[4];
    const float* Wv   = (const float*)d_in[5];
    const float* bv   = (const float*)d_in[6];
    const float* W1   = (const float*)d_in[7];
    const float* b1   = (const float*)d_in[8];
    const float* W2   = (const float*)d_in[9];
    const float* b2   = (const float*)d_in[10];
    const float* ln_g = (const float*)d_in[11];
    const float* ln_b = (const float*)d_in[12];
    const float* Wc   = (const float*)d_in[13];
    const float* bc   = (const float*)d_in[14];
    const float* We   = (const float*)d_in[15];
    const float* be   = (const float*)d_in[16];

    const size_t SZ = (size_t)M_ * A_;       // 4,194,304 floats
    float* ws   = (float*)d_ws;
    float* qb   = ws;                        // [BH, N, D]
    float* kb   = qb + SZ;
    float* vb   = kb + SZ;
    float* attn = vb + SZ;                   // [B, N, A] (becomes roll in-place)
    float* step = attn + SZ;                 // [B, N, A]
    float* part = step + SZ;                 // [B, 32, A]

    const dim3 ggemm(M_ / BM, A_ / BN);      // (256, 4)
    const float* cur = X;

    for (int i = 0; i < 3; ++i) {
        const float* Wq_i = Wq + (size_t)i * A_ * A_;
        const float* Wk_i = Wk + (size_t)i * A_ * A_;
        const float* Wv_i = Wv + (size_t)i * A_ * A_;
        const float* W1_i = W1 + (size_t)i * A_ * FFN_;
        const float* W2_i = W2 + (size_t)i * FFN_ * A_;

        gemm_kernel<false, true><<<ggemm, 256, 0, stream>>>(cur, Wq_i, bq + i * A_, qb, M_, A_, A_);
        gemm_kernel<false, true><<<ggemm, 256, 0, stream>>>(cur, Wk_i, bk + i * A_, kb, M_, A_, A_);
        gemm_kernel<false, true><<<ggemm, 256, 0, stream>>>(cur, Wv_i, bv + i * A_, vb, M_, A_, A_);

        attn_kernel<<<dim3(B_ * H_, N_ / TQ), 256, 0, stream>>>(qb, kb, vb, attn);

        ffn_kernel<8><<<M_ / 8, 256, 0, stream>>>(attn, W1_i, b1 + i * FFN_, W2_i, b2 + i * A_);

        add_ln_kernel<<<M_, 256, 0, stream>>>(attn, cur, ln_g, ln_b, step);
        cur = step;
    }

    // head: ent = relu(step @ Wc + bc) into qb; pool; final linear
    gemm_kernel<true, false><<<ggemm, 256, 0, stream>>>(cur, Wc, bc, qb, M_, A_, A_);
    pool_kernel<<<dim3(B_, 32), 256, 0, stream>>>(qb, part);
    final_kernel<<<B_, 256, 0, stream>>>(part, We, be, (float*)d_out);
}

// Round 2
// 676.920 us; speedup vs baseline: 16.8428x; 16.8428x over previous
//
#include <hip/hip_runtime.h>
#include <hip/hip_bf16.h>
#include <cstddef>

#define B_   16
#define N_   1024
#define H_   2
#define D_   128
#define A_   256
#define FFN_ 1024
#define M_   (B_ * N_)   // 16384 rows
#define EPS_ 1e-5f

typedef short  short8  __attribute__((ext_vector_type(8)));
typedef float  f32x16  __attribute__((ext_vector_type(16)));
typedef unsigned int uint;
typedef unsigned short ushort;

#define MFMA32(a, b, c) __builtin_amdgcn_mfma_f32_32x32x16_bf16(a, b, c, 0, 0, 0)

__device__ __forceinline__ uint f2b1(float x) {
    uint u = __float_as_uint(x);
    return (u + 0x7fffu + ((u >> 16) & 1u)) >> 16;
}
__device__ __forceinline__ uint f2b2(float lo, float hi) {
    return f2b1(lo) | (f2b1(hi) << 16);
}

// ---------------------------------------------------------------------------
// Weight prep: W[K][N] fp32  ->  Wt[N][K] bf16   (32x32 LDS tile transpose)
// ---------------------------------------------------------------------------
__global__ __launch_bounds__(256) void transpose_bf16_kernel(
    const float* __restrict__ W, ushort* __restrict__ Wt, int K, int N)
{
    __shared__ float tile[32][33];
    const int n0 = blockIdx.x * 32, k0 = blockIdx.y * 32;
    const int tc = threadIdx.x & 31, tr = threadIdx.x >> 5;
#pragma unroll
    for (int it = 0; it < 4; ++it) {
        int r = it * 8 + tr;
        tile[r][tc] = W[(size_t)(k0 + r) * N + n0 + tc];
    }
    __syncthreads();
#pragma unroll
    for (int it = 0; it < 4; ++it) {
        int r = it * 8 + tr;   // row of Wt (n index)
        Wt[(size_t)(n0 + r) * K + k0 + tc] = (ushort)f2b1(tile[tc][r]);
    }
}

// ---------------------------------------------------------------------------
// MFMA GEMM: out = epilogue(A[M,K] @ Wt^T + bias)
//   A: fp32 (ABF16=false) or bf16 (true), Wt: bf16 [Nout][K] (pre-transposed)
//   block: 256 thr = 4 waves (2x2), tile 128x128, wave-tile 64x64, K-chunk 64
// Epilogue modes: 1 = relu fp32 (ldc)   2 = relu bf16 (ldc)
//                 3 = bf16 heads [bh][n][d]   4 = bf16 transposed [bh][d][n]
// ---------------------------------------------------------------------------
template <bool ABF16>
__global__ __launch_bounds__(256) void gemm_mfma(
    const void* __restrict__ Asrc, const ushort* __restrict__ Wt,
    const float* __restrict__ bias, void* __restrict__ outp,
    int K, int ldc, int mode)
{
    __shared__ ushort sA[128 * 72];
    __shared__ ushort sB[128 * 72];

    const int tid = threadIdx.x;
    const int wid = tid >> 6, lane = tid & 63;
    const int c = lane & 31, g = lane >> 5;
    const int wr = wid >> 1, wc = wid & 1;
    const int m0 = blockIdx.x * 128;
    const int n0 = blockIdx.y * 128;

    f32x16 acc[2][2] = {};

    for (int k0 = 0; k0 < K; k0 += 64) {
        __syncthreads();
        if (ABF16) {
            const ushort* Ab = (const ushort*)Asrc;
#pragma unroll
            for (int it = 0; it < 4; ++it) {
                int idx = it * 256 + tid, r = idx >> 3, cc = (idx & 7) * 8;
                *(uint4*)&sA[r * 72 + cc] =
                    *(const uint4*)(Ab + (size_t)(m0 + r) * K + k0 + cc);
            }
        } else {
            const float* Af = (const float*)Asrc;
#pragma unroll
            for (int it = 0; it < 8; ++it) {
                int idx = it * 256 + tid, r = idx >> 4, cc = (idx & 15) * 4;
                float4 v = *(const float4*)(Af + (size_t)(m0 + r) * K + k0 + cc);
                uint2 w = { f2b2(v.x, v.y), f2b2(v.z, v.w) };
                *(uint2*)&sA[r * 72 + cc] = w;
            }
        }
#pragma unroll
        for (int it = 0; it < 4; ++it) {
            int idx = it * 256 + tid, r = idx >> 3, cc = (idx & 7) * 8;
            *(uint4*)&sB[r * 72 + cc] =
                *(const uint4*)(Wt + (size_t)(n0 + r) * K + k0 + cc);
        }
        __syncthreads();
#pragma unroll
        for (int ks = 0; ks < 4; ++ks) {
            const int ko = ks * 16 + 8 * g;
            short8 a0 = *(const short8*)&sA[(wr * 64 + c) * 72 + ko];
            short8 a1 = *(const short8*)&sA[(wr * 64 + 32 + c) * 72 + ko];
            short8 b0 = *(const short8*)&sB[(wc * 64 + c) * 72 + ko];
            short8 b1 = *(const short8*)&sB[(wc * 64 + 32 + c) * 72 + ko];
            acc[0][0] = MFMA32(a0, b0, acc[0][0]);
            acc[0][1] = MFMA32(a0, b1, acc[0][1]);
            acc[1][0] = MFMA32(a1, b0, acc[1][0]);
            acc[1][1] = MFMA32(a1, b1, acc[1][1]);
        }
    }

    const float bz[2] = { bias[n0 + wc * 64 + c], bias[n0 + wc * 64 + 32 + c] };

#pragma unroll
    for (int mr = 0; mr < 2; ++mr) {
#pragma unroll
        for (int ct = 0; ct < 2; ++ct) {
            const int colbase = n0 + wc * 64 + ct * 32 + c;
#pragma unroll
            for (int rg = 0; rg < 4; ++rg) {
                const int row = m0 + wr * 64 + mr * 32 + 8 * rg + 4 * g;
                float v0 = acc[mr][ct][4 * rg + 0] + bz[ct];
                float v1 = acc[mr][ct][4 * rg + 1] + bz[ct];
                float v2 = acc[mr][ct][4 * rg + 2] + bz[ct];
                float v3 = acc[mr][ct][4 * rg + 3] + bz[ct];
                if (mode == 1 || mode == 2) {
                    v0 = fmaxf(v0, 0.f); v1 = fmaxf(v1, 0.f);
                    v2 = fmaxf(v2, 0.f); v3 = fmaxf(v3, 0.f);
                }
                if (mode == 1) {
                    float* o = (float*)outp;
                    o[(size_t)(row + 0) * ldc + colbase] = v0;
                    o[(size_t)(row + 1) * ldc + colbase] = v1;
                    o[(size_t)(row + 2) * ldc + colbase] = v2;
                    o[(size_t)(row + 3) * ldc + colbase] = v3;
                } else if (mode == 2) {
                    ushort* o = (ushort*)outp;
                    o[(size_t)(row + 0) * ldc + colbase] = (ushort)f2b1(v0);
                    o[(size_t)(row + 1) * ldc + colbase] = (ushort)f2b1(v1);
                    o[(size_t)(row + 2) * ldc + colbase] = (ushort)f2b1(v2);
                    o[(size_t)(row + 3) * ldc + colbase] = (ushort)f2b1(v3);
                } else if (mode == 3) {
                    // q/k: [b*H+h][n][d]
                    ushort* o = (ushort*)outp;
                    const int hh = colbase >> 7, dd = colbase & (D_ - 1);
#pragma unroll
                    for (int r2 = 0; r2 < 4; ++r2) {
                        int rw = row + r2;
                        int bb = rw >> 10, np = rw & (N_ - 1);
                        float vv = (r2 == 0 ? v0 : r2 == 1 ? v1 : r2 == 2 ? v2 : v3);
                        o[(((size_t)(bb * H_ + hh) * N_ + np) * D_) + dd] = (ushort)f2b1(vv);
                    }
                } else {
                    // vt: [b*H+h][d][n], pack 4 consecutive n
                    ushort* o = (ushort*)outp;
                    const int hh = colbase >> 7, dd = colbase & (D_ - 1);
                    const int bb = row >> 10, np = row & (N_ - 1);
                    uint2 w = { f2b2(v0, v1), f2b2(v2, v3) };
                    *(uint2*)(o + ((size_t)(bb * H_ + hh) * D_ + dd) * N_ + np) = w;
                }
            }
        }
    }
}

// ---------------------------------------------------------------------------
// Flash attention, MFMA, swapped operands.
// block = 128 thr (2 waves), each wave owns 32 queries; K-tile = 64 keys.
// S^T = K·Q^T  (lane-local softmax per q = lane&31), O^T = V^T·P^T.
// q,k: bf16 [bh][n][d]; vt: bf16 [bh][d][n]; out: fp32 [b][n][A]
// ---------------------------------------------------------------------------
__global__ __launch_bounds__(128) void attn_kernel(
    const ushort* __restrict__ qg, const ushort* __restrict__ kg,
    const ushort* __restrict__ vtg, float* __restrict__ out)
{
    __shared__ ushort sK[64 * 136];
    __shared__ ushort sVt[128 * 72];

    const int tid = threadIdx.x;
    const int w = tid >> 6, lane = tid & 63;
    const int c = lane & 31, g = lane >> 5;
    const int bh = blockIdx.y, qt = blockIdx.x;
    const int q0 = qt * 64 + w * 32;
    const size_t bhoff = (size_t)bh * (N_ * D_);
    const float scale = 0.08838834764831845f;  // 1/sqrt(128)

    // Q fragments (B-operand: B[k=d][col=q], lane reads its own q-row)
    short8 qf[8];
    const ushort* qrow = qg + bhoff + (size_t)(q0 + c) * D_;
#pragma unroll
    for (int ks = 0; ks < 8; ++ks)
        qf[ks] = *(const short8*)(qrow + ks * 16 + 8 * g);

    f32x16 oacc[4] = {};
    float m = -1e30f, l = 0.f;

    for (int kt = 0; kt < N_ / 64; ++kt) {
        __syncthreads();
        {   // stage K tile [64 keys][128 d]
            const ushort* kb = kg + bhoff + (size_t)kt * 64 * D_;
#pragma unroll
            for (int it = 0; it < 8; ++it) {
                int idx = it * 128 + tid, key = idx >> 4, cc = (idx & 15) * 8;
                *(uint4*)&sK[key * 136 + cc] =
                    *(const uint4*)(kb + (size_t)key * D_ + cc);
            }
        }
        {   // stage Vt tile [128 d][64 keys]
            const ushort* vb = vtg + (size_t)bh * (D_ * N_) + kt * 64;
#pragma unroll
            for (int it = 0; it < 8; ++it) {
                int idx = it * 128 + tid, dd = idx >> 3, cc = (idx & 7) * 8;
                *(uint4*)&sVt[dd * 72 + cc] =
                    *(const uint4*)(vb + (size_t)dd * N_ + cc);
            }
        }
        __syncthreads();

        // ---- S^T = K · Q^T ----
        f32x16 sacc[2] = {};
#pragma unroll
        for (int kr = 0; kr < 2; ++kr)
#pragma unroll
            for (int ks = 0; ks < 8; ++ks) {
                short8 a = *(const short8*)&sK[(kr * 32 + c) * 136 + ks * 16 + 8 * g];
                sacc[kr] = MFMA32(a, qf[ks], sacc[kr]);
            }

        // ---- online softmax (q = lane&31 is lane-local) ----
        float p[32];
        float tmax = -1e30f;
#pragma unroll
        for (int kr = 0; kr < 2; ++kr)
#pragma unroll
            for (int r = 0; r < 16; ++r) {
                float s = sacc[kr][r] * scale;
                p[kr * 16 + r] = s;
                tmax = fmaxf(tmax, s);
            }
        tmax = fmaxf(tmax, __shfl_xor(tmax, 32, 64));
        const float mnew = fmaxf(m, tmax);
        const float corr = __expf(m - mnew);
        float tsum = 0.f;
#pragma unroll
        for (int j = 0; j < 32; ++j) {
            p[j] = __expf(p[j] - mnew);
            tsum += p[j];
        }
        tsum += __shfl_xor(tsum, 32, 64);
        l = l * corr + tsum;
        m = mnew;
#pragma unroll
        for (int dt = 0; dt < 4; ++dt)
#pragma unroll
            for (int r = 0; r < 16; ++r) oacc[dt][r] *= corr;

        // pack P rows to bf16 pairs (reg order)
        uint pk[16];
#pragma unroll
        for (int kr = 0; kr < 2; ++kr)
#pragma unroll
            for (int pp = 0; pp < 8; ++pp)
                pk[kr * 8 + pp] = f2b2(p[kr * 16 + 2 * pp], p[kr * 16 + 2 * pp + 1]);

        // ---- O^T += V^T · P^T ----
#pragma unroll
        for (int kb = 0; kb < 4; ++kb) {
            const int kr = kb >> 1;
            union { uint u[4]; short8 s; } pf;
#pragma unroll
            for (int j = 0; j < 4; ++j) {
                const int h = j >> 1;
                const int pi0 = (j & 1) + 4 * (kb & 1);
                uint v0 = (uint)__shfl((int)pk[kr * 8 + pi0],     c + 32 * h, 64);
                uint v1 = (uint)__shfl((int)pk[kr * 8 + pi0 + 2], c + 32 * h, 64);
                pf.u[j] = g ? v1 : v0;
            }
#pragma unroll
            for (int dt = 0; dt < 4; ++dt) {
                short8 a = *(const short8*)&sVt[(dt * 32 + c) * 72 + kb * 16 + 8 * g];
                oacc[dt] = MFMA32(a, pf.s, oacc[dt]);
            }
        }
    }

    // ---- epilogue: out[b][q][h*128 + d] ----
    const float inv = 1.f / l;
    const int bb = bh >> 1, hh = bh & 1;
    float* ob = out + ((size_t)(bb * N_ + q0 + c)) * A_ + hh * D_;
#pragma unroll
    for (int dt = 0; dt < 4; ++dt)
#pragma unroll
        for (int rg = 0; rg < 4; ++rg) {
            float4 v = { oacc[dt][4 * rg + 0] * inv, oacc[dt][4 * rg + 1] * inv,
                         oacc[dt][4 * rg + 2] * inv, oacc[dt][4 * rg + 3] * inv };
            *(float4*)(ob + dt * 32 + 8 * rg + 4 * g) = v;
        }
}

// ---------------------------------------------------------------------------
// step = LayerNorm(roll + prev) * g + b  — one block per row
// ---------------------------------------------------------------------------
__global__ __launch_bounds__(256) void add_ln_kernel(
    const float* __restrict__ roll, const float* __restrict__ prev,
    const float* __restrict__ g, const float* __restrict__ bta,
    float* __restrict__ out)
{
    const int row = blockIdx.x, tid = threadIdx.x;
    float v = roll[(size_t)row * A_ + tid] + prev[(size_t)row * A_ + tid];
    float s = v, s2 = v * v;
#pragma unroll
    for (int o = 32; o > 0; o >>= 1) {
        s  += __shfl_down(s, o, 64);
        s2 += __shfl_down(s2, o, 64);
    }
    __shared__ float ps[4], ps2[4];
    __shared__ float mu_s, rsig_s;
    const int wid = tid >> 6, lane = tid & 63;
    if (lane == 0) { ps[wid] = s; ps2[wid] = s2; }
    __syncthreads();
    if (tid == 0) {
        float S  = ps[0] + ps[1] + ps[2] + ps[3];
        float S2 = ps2[0] + ps2[1] + ps2[2] + ps2[3];
        float mu = S / A_;
        float var = S2 / A_ - mu * mu;
        mu_s = mu;
        rsig_s = rsqrtf(var + EPS_);
    }
    __syncthreads();
    out[(size_t)row * A_ + tid] = (v - mu_s) * rsig_s * g[tid] + bta[tid];
}

// ---------------------------------------------------------------------------
__global__ __launch_bounds__(256) void pool_kernel(
    const float* __restrict__ ent, float* __restrict__ part)
{
    const int b = blockIdx.x, s = blockIdx.y, a = threadIdx.x;
    float acc = 0.f;
    for (int n = s * 32; n < s * 32 + 32; ++n)
        acc += ent[((size_t)b * N_ + n) * A_ + a];
    part[((size_t)b * 32 + s) * A_ + a] = acc;
}

__global__ __launch_bounds__(256) void final_kernel(
    const float* __restrict__ part, const float* __restrict__ We,
    const float* __restrict__ be, float* __restrict__ out)
{
    __shared__ float sp[A_];
    const int b = blockIdx.x, tid = threadIdx.x;
    float s = 0.f;
    for (int j = 0; j < 32; ++j) s += part[((size_t)b * 32 + j) * A_ + tid];
    sp[tid] = s * (1.0f / N_);
    __syncthreads();
    float acc = be[tid];
    for (int kk = 0; kk < A_; ++kk) acc += sp[kk] * We[(size_t)kk * A_ + tid];
    out[b * A_ + tid] = fmaxf(acc, 0.f);
}

// ---------------------------------------------------------------------------
extern "C" void kernel_launch(void* const* d_in, const int* in_sizes, int n_in,
                              void* d_out, int out_size, void* d_ws, size_t ws_size,
                              hipStream_t stream)
{
    const float* X    = (const float*)d_in[0];
    const float* Wq   = (const float*)d_in[1];
    const float* bq   = (const float*)d_in[2];
    const float* Wk   = (const float*)d_in[3];
    const float* bk   = (const float*)d_in[4];
    const float* Wv   = (const float*)d_in[5];
    const float* bv   = (const float*)d_in[6];
    const float* W1   = (const float*)d_in[7];
    const float* b1   = (const float*)d_in[8];
    const float* W2   = (const float*)d_in[9];
    const float* b2   = (const float*)d_in[10];
    const float* ln_g = (const float*)d_in[11];
    const float* ln_b = (const float*)d_in[12];
    const float* Wc   = (const float*)d_in[13];
    const float* bc   = (const float*)d_in[14];
    const float* We   = (const float*)d_in[15];
    const float* be   = (const float*)d_in[16];

    // ---- workspace layout ----
    char* base = (char*)d_ws;
    const size_t QKV_E = (size_t)B_ * H_ * N_ * D_;   // 4.19M bf16 elems
    ushort* qb   = (ushort*)base;                base += QKV_E * 2;
    ushort* kb   = (ushort*)base;                base += QKV_E * 2;
    ushort* vt   = (ushort*)base;                base += QKV_E * 2;
    ushort* hbuf = (ushort*)base;                base += (size_t)M_ * FFN_ * 2;
    float*  attn = (float*)base;                 base += (size_t)M_ * A_ * 4;
    float*  step = (float*)base;                 base += (size_t)M_ * A_ * 4;
    ushort* wq_t = (ushort*)base;                base += (size_t)3 * A_ * A_ * 2;
    ushort* wk_t = (ushort*)base;                base += (size_t)3 * A_ * A_ * 2;
    ushort* wv_t = (ushort*)base;                base += (size_t)3 * A_ * A_ * 2;
    ushort* w1_t = (ushort*)base;                base += (size_t)3 * A_ * FFN_ * 2;
    ushort* w2_t = (ushort*)base;                base += (size_t)3 * FFN_ * A_ * 2;
    ushort* wc_t = (ushort*)base;                base += (size_t)A_ * A_ * 2;
    float*  part = (float*)base;                 base += (size_t)B_ * 32 * A_ * 4;
    float*  ent  = (float*)hbuf;  // head output reuses hbuf (free by then)

    // ---- weight prep (transpose + bf16) ----
    for (int i = 0; i < 3; ++i) {
        transpose_bf16_kernel<<<dim3(A_/32, A_/32), 256, 0, stream>>>(
            Wq + (size_t)i*A_*A_, wq_t + (size_t)i*A_*A_, A_, A_);
        transpose_bf16_kernel<<<dim3(A_/32, A_/32), 256, 0, stream>>>(
            Wk + (size_t)i*A_*A_, wk_t + (size_t)i*A_*A_, A_, A_);
        transpose_bf16_kernel<<<dim3(A_/32, A_/32), 256, 0, stream>>>(
            Wv + (size_t)i*A_*A_, wv_t + (size_t)i*A_*A_, A_, A_);
        transpose_bf16_kernel<<<dim3(FFN_/32, A_/32), 256, 0, stream>>>(
            W1 + (size_t)i*A_*FFN_, w1_t + (size_t)i*A_*FFN_, A_, FFN_);
        transpose_bf16_kernel<<<dim3(A_/32, FFN_/32), 256, 0, stream>>>(
            W2 + (size_t)i*FFN_*A_, w2_t + (size_t)i*FFN_*A_, FFN_, A_);
    }
    transpose_bf16_kernel<<<dim3(A_/32, A_/32), 256, 0, stream>>>(Wc, wc_t, A_, A_);

    const float* cur = X;
    for (int i = 0; i < 3; ++i) {
        gemm_mfma<false><<<dim3(M_/128, 2), 256, 0, stream>>>(
            cur, wq_t + (size_t)i*A_*A_, bq + i*A_, qb, A_, 0, 3);
        gemm_mfma<false><<<dim3(M_/128, 2), 256, 0, stream>>>(
            cur, wk_t + (size_t)i*A_*A_, bk + i*A_, kb, A_, 0, 3);
        gemm_mfma<false><<<dim3(M_/128, 2), 256, 0, stream>>>(
            cur, wv_t + (size_t)i*A_*A_, bv + i*A_, vt, A_, 0, 4);

        attn_kernel<<<dim3(N_/64, B_*H_), 128, 0, stream>>>(qb, kb, vt, attn);

        gemm_mfma<false><<<dim3(M_/128, FFN_/128), 256, 0, stream>>>(
            attn, w1_t + (size_t)i*A_*FFN_, b1 + i*FFN_, hbuf, A_, FFN_, 2);
        gemm_mfma<true><<<dim3(M_/128, A_/128), 256, 0, stream>>>(
            hbuf, w2_t + (size_t)i*FFN_*A_, b2 + i*A_, attn, FFN_, A_, 1);

        add_ln_kernel<<<M_, 256, 0, stream>>>(attn, cur, ln_g, ln_b, step);
        cur = step;
    }

    // head
    gemm_mfma<false><<<dim3(M_/128, A_/128), 256, 0, stream>>>(
        cur, wc_t, bc, ent, A_, A_, 1);
    pool_kernel<<<dim3(B_, 32), 256, 0, stream>>>(ent, part);
    final_kernel<<<B_, 256, 0, stream>>>(part, We, be, (float*)d_out);
}

// Round 3
// 676.841 us; speedup vs baseline: 16.8448x; 1.0001x over previous
//
#include <hip/hip_runtime.h>
#include <hip/hip_bf16.h>
#include <cstddef>

#define B_   16
#define N_   1024
#define H_   2
#define D_   128
#define A_   256
#define FFN_ 1024
#define M_   (B_ * N_)   // 16384 rows
#define EPS_ 1e-5f
#define SPLIT 4
#define KT   32                    // keys per tile
#define TPC  (N_ / SPLIT / KT)     // tiles per chunk = 8
#define QKV_E ((size_t)B_ * H_ * N_ * D_)

typedef short  short8  __attribute__((ext_vector_type(8)));
typedef float  f32x16  __attribute__((ext_vector_type(16)));
typedef unsigned int uint;
typedef unsigned short ushort;

#define MFMA32(a, b, c) __builtin_amdgcn_mfma_f32_32x32x16_bf16(a, b, c, 0, 0, 0)

__device__ __forceinline__ uint f2b1(float x) {
    uint u = __float_as_uint(x);
    return (u + 0x7fffu + ((u >> 16) & 1u)) >> 16;
}
__device__ __forceinline__ uint f2b2(float lo, float hi) {
    return f2b1(lo) | (f2b1(hi) << 16);
}
__device__ __forceinline__ float b2f(ushort u) {
    return __uint_as_float(((uint)u) << 16);
}

// ---------------------------------------------------------------------------
// Weight prep: W[K][N] fp32 -> Wt[N][K] bf16, blockIdx.z = layer (strided)
// ---------------------------------------------------------------------------
__global__ __launch_bounds__(256) void transpose_bf16_kernel(
    const float* __restrict__ W, ushort* __restrict__ Wt, int K, int N,
    size_t sstride, size_t dstride)
{
    __shared__ float tile[32][33];
    W  += (size_t)blockIdx.z * sstride;
    Wt += (size_t)blockIdx.z * dstride;
    const int n0 = blockIdx.x * 32, k0 = blockIdx.y * 32;
    const int tc = threadIdx.x & 31, tr = threadIdx.x >> 5;
#pragma unroll
    for (int it = 0; it < 4; ++it) {
        int r = it * 8 + tr;
        tile[r][tc] = W[(size_t)(k0 + r) * N + n0 + tc];
    }
    __syncthreads();
#pragma unroll
    for (int it = 0; it < 4; ++it) {
        int r = it * 8 + tr;
        Wt[(size_t)(n0 + r) * K + k0 + tc] = (ushort)f2b1(tile[tc][r]);
    }
}

// packed QKV transpose: z = layer*3 + sec, dst rows [sec*256 .. sec*256+255]
__global__ __launch_bounds__(256) void transpose_qkv_kernel(
    const float* __restrict__ Wq, const float* __restrict__ Wk,
    const float* __restrict__ Wv, ushort* __restrict__ dst)
{
    __shared__ float tile[32][33];
    const int layer = blockIdx.z / 3, sec = blockIdx.z % 3;
    const float* W = (sec == 0 ? Wq : sec == 1 ? Wk : Wv) + (size_t)layer * A_ * A_;
    ushort* out = dst + (size_t)layer * (3 * A_ * A_) + (size_t)sec * A_ * A_;
    const int n0 = blockIdx.x * 32, k0 = blockIdx.y * 32;
    const int tc = threadIdx.x & 31, tr = threadIdx.x >> 5;
#pragma unroll
    for (int it = 0; it < 4; ++it) {
        int r = it * 8 + tr;
        tile[r][tc] = W[(size_t)(k0 + r) * A_ + n0 + tc];
    }
    __syncthreads();
#pragma unroll
    for (int it = 0; it < 4; ++it) {
        int r = it * 8 + tr;
        out[(size_t)(n0 + r) * A_ + k0 + tc] = (ushort)f2b1(tile[tc][r]);
    }
}

// ---------------------------------------------------------------------------
// MFMA GEMM: out = epilogue(A[M,K] @ Wt^T + bias)
// modes: 1 = relu fp32 (ldc)   2 = relu bf16 (ldc)
//        5 = fused QKV: cols 0-255 -> q heads, 256-511 -> k heads,
//            512-767 -> v transposed [bh][d][n]; outp = q base (contiguous)
// ---------------------------------------------------------------------------
template <bool ABF16>
__global__ __launch_bounds__(256) void gemm_mfma(
    const void* __restrict__ Asrc, const ushort* __restrict__ Wt,
    const float* __restrict__ bias, const float* __restrict__ biasK,
    const float* __restrict__ biasV, void* __restrict__ outp,
    int K, int ldc, int mode)
{
    __shared__ ushort sA[128 * 72];
    __shared__ ushort sB[128 * 72];

    const int tid = threadIdx.x;
    const int wid = tid >> 6, lane = tid & 63;
    const int c = lane & 31, g = lane >> 5;
    const int wr = wid >> 1, wc = wid & 1;
    const int m0 = blockIdx.x * 128;
    const int n0 = blockIdx.y * 128;

    f32x16 acc[2][2] = {};

    for (int k0 = 0; k0 < K; k0 += 64) {
        __syncthreads();
        if (ABF16) {
            const ushort* Ab = (const ushort*)Asrc;
#pragma unroll
            for (int it = 0; it < 4; ++it) {
                int idx = it * 256 + tid, r = idx >> 3, cc = (idx & 7) * 8;
                *(uint4*)&sA[r * 72 + cc] =
                    *(const uint4*)(Ab + (size_t)(m0 + r) * K + k0 + cc);
            }
        } else {
            const float* Af = (const float*)Asrc;
#pragma unroll
            for (int it = 0; it < 8; ++it) {
                int idx = it * 256 + tid, r = idx >> 4, cc = (idx & 15) * 4;
                float4 v = *(const float4*)(Af + (size_t)(m0 + r) * K + k0 + cc);
                uint2 w = { f2b2(v.x, v.y), f2b2(v.z, v.w) };
                *(uint2*)&sA[r * 72 + cc] = w;
            }
        }
#pragma unroll
        for (int it = 0; it < 4; ++it) {
            int idx = it * 256 + tid, r = idx >> 3, cc = (idx & 7) * 8;
            *(uint4*)&sB[r * 72 + cc] =
                *(const uint4*)(Wt + (size_t)(n0 + r) * K + k0 + cc);
        }
        __syncthreads();
#pragma unroll
        for (int ks = 0; ks < 4; ++ks) {
            const int ko = ks * 16 + 8 * g;
            short8 a0 = *(const short8*)&sA[(wr * 64 + c) * 72 + ko];
            short8 a1 = *(const short8*)&sA[(wr * 64 + 32 + c) * 72 + ko];
            short8 b0 = *(const short8*)&sB[(wc * 64 + c) * 72 + ko];
            short8 b1 = *(const short8*)&sB[(wc * 64 + 32 + c) * 72 + ko];
            acc[0][0] = MFMA32(a0, b0, acc[0][0]);
            acc[0][1] = MFMA32(a0, b1, acc[0][1]);
            acc[1][0] = MFMA32(a1, b0, acc[1][0]);
            acc[1][1] = MFMA32(a1, b1, acc[1][1]);
        }
    }

    const int sec = n0 >> 8;  // for mode 5 (block-uniform)
    const float* bp = bias;
    int nw = n0;
    if (mode == 5) {
        bp = (sec == 0 ? bias : sec == 1 ? biasK : biasV);
        nw = n0 & 255;
    }
    const float bz[2] = { bp[nw + wc * 64 + c], bp[nw + wc * 64 + 32 + c] };

#pragma unroll
    for (int mr = 0; mr < 2; ++mr) {
#pragma unroll
        for (int ct = 0; ct < 2; ++ct) {
            const int colbase = n0 + wc * 64 + ct * 32 + c;
#pragma unroll
            for (int rg = 0; rg < 4; ++rg) {
                const int row = m0 + wr * 64 + mr * 32 + 8 * rg + 4 * g;
                float v0 = acc[mr][ct][4 * rg + 0] + bz[ct];
                float v1 = acc[mr][ct][4 * rg + 1] + bz[ct];
                float v2 = acc[mr][ct][4 * rg + 2] + bz[ct];
                float v3 = acc[mr][ct][4 * rg + 3] + bz[ct];
                if (mode == 1 || mode == 2) {
                    v0 = fmaxf(v0, 0.f); v1 = fmaxf(v1, 0.f);
                    v2 = fmaxf(v2, 0.f); v3 = fmaxf(v3, 0.f);
                }
                if (mode == 1) {
                    float* o = (float*)outp;
                    o[(size_t)(row + 0) * ldc + colbase] = v0;
                    o[(size_t)(row + 1) * ldc + colbase] = v1;
                    o[(size_t)(row + 2) * ldc + colbase] = v2;
                    o[(size_t)(row + 3) * ldc + colbase] = v3;
                } else if (mode == 2) {
                    ushort* o = (ushort*)outp;
                    o[(size_t)(row + 0) * ldc + colbase] = (ushort)f2b1(v0);
                    o[(size_t)(row + 1) * ldc + colbase] = (ushort)f2b1(v1);
                    o[(size_t)(row + 2) * ldc + colbase] = (ushort)f2b1(v2);
                    o[(size_t)(row + 3) * ldc + colbase] = (ushort)f2b1(v3);
                } else {  // mode 5
                    const int cw = colbase & 255;
                    const int hh = cw >> 7, dd = cw & (D_ - 1);
                    if (sec < 2) {
                        ushort* o = (ushort*)outp + (size_t)sec * QKV_E;
#pragma unroll
                        for (int r2 = 0; r2 < 4; ++r2) {
                            int rw = row + r2;
                            int bb = rw >> 10, np = rw & (N_ - 1);
                            float vv = (r2 == 0 ? v0 : r2 == 1 ? v1 : r2 == 2 ? v2 : v3);
                            o[(((size_t)(bb * H_ + hh) * N_ + np) * D_) + dd] = (ushort)f2b1(vv);
                        }
                    } else {
                        ushort* o = (ushort*)outp + 2 * QKV_E;
                        const int bb = row >> 10, np = row & (N_ - 1);
                        uint2 w = { f2b2(v0, v1), f2b2(v2, v3) };
                        *(uint2*)(o + ((size_t)(bb * H_ + hh) * D_ + dd) * N_ + np) = w;
                    }
                }
            }
        }
    }
}

// ---------------------------------------------------------------------------
// Flash attention with grid split-KV.
// block = 128 thr (2 waves x 32 queries), KV chunk = 256 keys, tile = 32 keys.
// Writes unnormalized partial O (bf16) + per-row m,l (exp2 domain).
// ---------------------------------------------------------------------------
__global__ __launch_bounds__(128) void attn_kernel(
    const ushort* __restrict__ qg, const ushort* __restrict__ kg,
    const ushort* __restrict__ vtg, ushort* __restrict__ po,
    float* __restrict__ pm, float* __restrict__ pl)
{
    __shared__ ushort sK[KT * 136];    // [32 keys][128 d + pad]
    __shared__ ushort sVt[128 * 40];   // [128 d][32 keys + pad]

    const int tid = threadIdx.x;
    const int w = tid >> 6, lane = tid & 63;
    const int c = lane & 31, g = lane >> 5;
    const int qt = blockIdx.x, bh = blockIdx.y, z = blockIdx.z;
    const int q0 = qt * 64 + w * 32;
    const size_t bhoff = (size_t)bh * (N_ * D_);
    const int kt0 = z * (N_ / SPLIT);
    const float scale2 = 0.08838834764831845f * 1.44269504f;  // /sqrt(128) * log2e
    const float THR = 11.5f;   // defer-max threshold (~8 nats)

    // Q fragments (B-operand)
    short8 qf[8];
    const ushort* qrow = qg + bhoff + (size_t)(q0 + c) * D_;
#pragma unroll
    for (int ks = 0; ks < 8; ++ks)
        qf[ks] = *(const short8*)(qrow + ks * 16 + 8 * g);

    f32x16 oacc[4] = {};
    float m = -1e30f, l = 0.f;

    uint4 kreg[4], vreg[4];
    auto loadK = [&](int t) {
        const ushort* src = kg + bhoff + (size_t)(kt0 + t * KT) * D_;
#pragma unroll
        for (int it = 0; it < 4; ++it) {
            int idx = it * 128 + tid;
            kreg[it] = *(const uint4*)(src + (size_t)(idx >> 4) * D_ + (idx & 15) * 8);
        }
    };
    auto loadV = [&](int t) {
        const ushort* src = vtg + bhoff + kt0 + t * KT;
#pragma unroll
        for (int it = 0; it < 4; ++it) {
            int idx = it * 128 + tid;
            vreg[it] = *(const uint4*)(src + (size_t)(idx >> 2) * N_ + (idx & 3) * 8);
        }
    };
    auto writeLDS = [&]() {
#pragma unroll
        for (int it = 0; it < 4; ++it) {
            int idx = it * 128 + tid;
            *(uint4*)&sK[(idx >> 4) * 136 + (idx & 15) * 8] = kreg[it];
        }
#pragma unroll
        for (int it = 0; it < 4; ++it) {
            int idx = it * 128 + tid;
            *(uint4*)&sVt[(idx >> 2) * 40 + (idx & 3) * 8] = vreg[it];
        }
    };

    loadK(0); loadV(0);
    writeLDS();
    __syncthreads();

    for (int t = 0; t < TPC; ++t) {
        if (t + 1 < TPC) { loadK(t + 1); loadV(t + 1); }

        // ---- S^T = K · Q^T  (32 keys x 32 q) ----
        f32x16 sacc = {};
#pragma unroll
        for (int ks = 0; ks < 8; ++ks) {
            short8 a = *(const short8*)&sK[c * 136 + ks * 16 + 8 * g];
            sacc = MFMA32(a, qf[ks], sacc);
        }

        // ---- online softmax in exp2 domain (q = lane&31 lane-local) ----
        float p[16];
        float tmax = -1e30f;
#pragma unroll
        for (int r = 0; r < 16; ++r) {
            float s = sacc[r] * scale2;
            p[r] = s;
            tmax = fmaxf(tmax, s);
        }
        tmax = fmaxf(tmax, __shfl_xor(tmax, 32, 64));
        if (!__all(tmax - m <= THR)) {
            const float mnew = fmaxf(m, tmax);
            const float corr = exp2f(m - mnew);
#pragma unroll
            for (int dt = 0; dt < 4; ++dt)
#pragma unroll
                for (int r = 0; r < 16; ++r) oacc[dt][r] *= corr;
            l *= corr;
            m = mnew;
        }
        float tsum = 0.f;
#pragma unroll
        for (int r = 0; r < 16; ++r) {
            p[r] = exp2f(p[r] - m);
            tsum += p[r];
        }
        tsum += __shfl_xor(tsum, 32, 64);
        l += tsum;

        // pack P to bf16 pairs
        uint pk[8];
#pragma unroll
        for (int pp = 0; pp < 8; ++pp)
            pk[pp] = f2b2(p[2 * pp], p[2 * pp + 1]);

        // cross-half exchange: partner (opposite g) values, 4 shuffles
        uint v0 = g ? pk[0] : pk[2];
        uint v1 = g ? pk[1] : pk[3];
        uint v2 = g ? pk[4] : pk[6];
        uint v3 = g ? pk[5] : pk[7];
        uint r0 = (uint)__shfl_xor((int)v0, 32, 64);
        uint r1 = (uint)__shfl_xor((int)v1, 32, 64);
        uint r2 = (uint)__shfl_xor((int)v2, 32, 64);
        uint r3 = (uint)__shfl_xor((int)v3, 32, 64);

        // ---- O^T += V^T · P^T ----
#pragma unroll
        for (int kb = 0; kb < 2; ++kb) {
            union { uint u[4]; short8 s; } pf;
            if (kb == 0) {
                pf.u[0] = g ? r0 : pk[0];
                pf.u[1] = g ? r1 : pk[1];
                pf.u[2] = g ? pk[2] : r0;
                pf.u[3] = g ? pk[3] : r1;
            } else {
                pf.u[0] = g ? r2 : pk[4];
                pf.u[1] = g ? r3 : pk[5];
                pf.u[2] = g ? pk[6] : r2;
                pf.u[3] = g ? pk[7] : r3;
            }
#pragma unroll
            for (int dt = 0; dt < 4; ++dt) {
                short8 a = *(const short8*)&sVt[(dt * 32 + c) * 40 + kb * 16 + 8 * g];
                oacc[dt] = MFMA32(a, pf.s, oacc[dt]);
            }
        }

        __syncthreads();
        if (t + 1 < TPC) { writeLDS(); __syncthreads(); }
    }

    // ---- write partials (unnormalized) ----
    const int rowq = q0 + c;
    const size_t pbase = ((size_t)(z * 32 + bh) * N_ + rowq) * D_;
#pragma unroll
    for (int dt = 0; dt < 4; ++dt)
#pragma unroll
        for (int rg = 0; rg < 4; ++rg) {
            int d = dt * 32 + 8 * rg + 4 * g;
            uint2 wv = { f2b2(oacc[dt][4 * rg + 0], oacc[dt][4 * rg + 1]),
                         f2b2(oacc[dt][4 * rg + 2], oacc[dt][4 * rg + 3]) };
            *(uint2*)(po + pbase + d) = wv;
        }
    if (lane < 32) {
        pm[(size_t)(z * 32 + bh) * N_ + rowq] = m;
        pl[(size_t)(z * 32 + bh) * N_ + rowq] = l;
    }
}

// ---------------------------------------------------------------------------
// Combine split-KV partials -> attn fp32 [b][n][A]
// ---------------------------------------------------------------------------
__global__ __launch_bounds__(256) void combine_kernel(
    const ushort* __restrict__ po, const float* __restrict__ pm,
    const float* __restrict__ pl, float* __restrict__ out)
{
    const int idx = blockIdx.x * 256 + threadIdx.x;
    const int row = idx >> 7, d = idx & 127;
    const int R = B_ * H_ * N_;  // 32768

    float ms[SPLIT];
    float M = -1e30f;
#pragma unroll
    for (int s = 0; s < SPLIT; ++s) {
        ms[s] = pm[(size_t)s * R + row];
        M = fmaxf(M, ms[s]);
    }
    float L = 0.f, acc = 0.f;
#pragma unroll
    for (int s = 0; s < SPLIT; ++s) {
        float wgt = exp2f(ms[s] - M);
        L += pl[(size_t)s * R + row] * wgt;
        acc += b2f(po[((size_t)s * R + row) * D_ + d]) * wgt;
    }
    const int bh = row >> 10, n = row & (N_ - 1);
    const int bb = bh >> 1, hh = bh & 1;
    out[((size_t)(bb * N_ + n)) * A_ + hh * D_ + d] = acc / L;
}

// ---------------------------------------------------------------------------
// step = LayerNorm(roll + prev) * g + b  — one block per row
// ---------------------------------------------------------------------------
__global__ __launch_bounds__(256) void add_ln_kernel(
    const float* __restrict__ roll, const float* __restrict__ prev,
    const float* __restrict__ g, const float* __restrict__ bta,
    float* __restrict__ out)
{
    const int row = blockIdx.x, tid = threadIdx.x;
    float v = roll[(size_t)row * A_ + tid] + prev[(size_t)row * A_ + tid];
    float s = v, s2 = v * v;
#pragma unroll
    for (int o = 32; o > 0; o >>= 1) {
        s  += __shfl_down(s, o, 64);
        s2 += __shfl_down(s2, o, 64);
    }
    __shared__ float ps[4], ps2[4];
    __shared__ float mu_s, rsig_s;
    const int wid = tid >> 6, lane = tid & 63;
    if (lane == 0) { ps[wid] = s; ps2[wid] = s2; }
    __syncthreads();
    if (tid == 0) {
        float S  = ps[0] + ps[1] + ps[2] + ps[3];
        float S2 = ps2[0] + ps2[1] + ps2[2] + ps2[3];
        float mu = S / A_;
        float var = S2 / A_ - mu * mu;
        mu_s = mu;
        rsig_s = rsqrtf(var + EPS_);
    }
    __syncthreads();
    out[(size_t)row * A_ + tid] = (v - mu_s) * rsig_s * g[tid] + bta[tid];
}

// ---------------------------------------------------------------------------
__global__ __launch_bounds__(256) void pool_kernel(
    const float* __restrict__ ent, float* __restrict__ part)
{
    const int b = blockIdx.x, s = blockIdx.y, a = threadIdx.x;
    float acc = 0.f;
    for (int n = s * 32; n < s * 32 + 32; ++n)
        acc += ent[((size_t)b * N_ + n) * A_ + a];
    part[((size_t)b * 32 + s) * A_ + a] = acc;
}

__global__ __launch_bounds__(256) void final_kernel(
    const float* __restrict__ part, const float* __restrict__ We,
    const float* __restrict__ be, float* __restrict__ out)
{
    __shared__ float sp[A_];
    const int b = blockIdx.x, tid = threadIdx.x;
    float s = 0.f;
    for (int j = 0; j < 32; ++j) s += part[((size_t)b * 32 + j) * A_ + tid];
    sp[tid] = s * (1.0f / N_);
    __syncthreads();
    float acc = be[tid];
    for (int kk = 0; kk < A_; ++kk) acc += sp[kk] * We[(size_t)kk * A_ + tid];
    out[b * A_ + tid] = fmaxf(acc, 0.f);
}

// ---------------------------------------------------------------------------
extern "C" void kernel_launch(void* const* d_in, const int* in_sizes, int n_in,
                              void* d_out, int out_size, void* d_ws, size_t ws_size,
                              hipStream_t stream)
{
    const float* X    = (const float*)d_in[0];
    const float* Wq   = (const float*)d_in[1];
    const float* bq   = (const float*)d_in[2];
    const float* Wk   = (const float*)d_in[3];
    const float* bk   = (const float*)d_in[4];
    const float* Wv   = (const float*)d_in[5];
    const float* bv   = (const float*)d_in[6];
    const float* W1   = (const float*)d_in[7];
    const float* b1   = (const float*)d_in[8];
    const float* W2   = (const float*)d_in[9];
    const float* b2   = (const float*)d_in[10];
    const float* ln_g = (const float*)d_in[11];
    const float* ln_b = (const float*)d_in[12];
    const float* Wc   = (const float*)d_in[13];
    const float* bc   = (const float*)d_in[14];
    const float* We   = (const float*)d_in[15];
    const float* be   = (const float*)d_in[16];

    // ---- workspace layout ----
    char* base = (char*)d_ws;
    ushort* qb     = (ushort*)base;  base += QKV_E * 2;        // q/k/vt contiguous
    /* kb = qb + QKV_E */            base += QKV_E * 2;
    /* vt = qb + 2*QKV_E */          base += QKV_E * 2;
    ushort* hbuf   = (ushort*)base;  base += (size_t)M_ * FFN_ * 2;  // aliases po
    float*  attn   = (float*)base;   base += (size_t)M_ * A_ * 4;
    float*  step   = (float*)base;   base += (size_t)M_ * A_ * 4;
    ushort* wqkv_t = (ushort*)base;  base += (size_t)3 * 3 * A_ * A_ * 2;
    ushort* w1_t   = (ushort*)base;  base += (size_t)3 * A_ * FFN_ * 2;
    ushort* w2_t   = (ushort*)base;  base += (size_t)3 * FFN_ * A_ * 2;
    ushort* wc_t   = (ushort*)base;  base += (size_t)A_ * A_ * 2;
    float*  part   = (float*)base;   base += (size_t)B_ * 32 * A_ * 4;
    float*  pm     = (float*)base;   base += (size_t)SPLIT * B_ * H_ * N_ * 4;
    float*  pl     = (float*)base;   base += (size_t)SPLIT * B_ * H_ * N_ * 4;
    ushort* kbuf   = qb + QKV_E;
    ushort* vtbuf  = qb + 2 * QKV_E;
    ushort* po     = hbuf;           // 32MB partial O, dead before FFN uses hbuf
    float*  ent    = (float*)hbuf;   // head output also reuses hbuf

    // ---- weight prep (4 launches) ----
    transpose_qkv_kernel<<<dim3(8, 8, 9), 256, 0, stream>>>(Wq, Wk, Wv, wqkv_t);
    transpose_bf16_kernel<<<dim3(FFN_/32, A_/32, 3), 256, 0, stream>>>(
        W1, w1_t, A_, FFN_, (size_t)A_ * FFN_, (size_t)A_ * FFN_);
    transpose_bf16_kernel<<<dim3(A_/32, FFN_/32, 3), 256, 0, stream>>>(
        W2, w2_t, FFN_, A_, (size_t)FFN_ * A_, (size_t)FFN_ * A_);
    transpose_bf16_kernel<<<dim3(A_/32, A_/32, 1), 256, 0, stream>>>(
        Wc, wc_t, A_, A_, 0, 0);

    const float* cur = X;
    for (int i = 0; i < 3; ++i) {
        // fused QKV projection
        gemm_mfma<false><<<dim3(M_/128, 6), 256, 0, stream>>>(
            cur, wqkv_t + (size_t)i * 3 * A_ * A_,
            bq + i * A_, bk + i * A_, bv + i * A_, qb, A_, 0, 5);

        attn_kernel<<<dim3(N_/64, B_*H_, SPLIT), 128, 0, stream>>>(
            qb, kbuf, vtbuf, po, pm, pl);
        combine_kernel<<<(B_*H_*N_*D_)/256, 256, 0, stream>>>(po, pm, pl, attn);

        gemm_mfma<false><<<dim3(M_/128, FFN_/128), 256, 0, stream>>>(
            attn, w1_t + (size_t)i * A_ * FFN_, b1 + i * FFN_, nullptr, nullptr,
            hbuf, A_, FFN_, 2);
        gemm_mfma<true><<<dim3(M_/128, A_/128), 256, 0, stream>>>(
            hbuf, w2_t + (size_t)i * FFN_ * A_, b2 + i * A_, nullptr, nullptr,
            attn, FFN_, A_, 1);

        add_ln_kernel<<<M_, 256, 0, stream>>>(attn, cur, ln_g, ln_b, step);
        cur = step;
    }

    // head
    gemm_mfma<false><<<dim3(M_/128, A_/128), 256, 0, stream>>>(
        cur, wc_t, bc, nullptr, nullptr, ent, A_, A_, 1);
    pool_kernel<<<dim3(B_, 32), 256, 0, stream>>>(ent, part);
    final_kernel<<<B_, 256, 0, stream>>>(part, We, be, (float*)d_out);
}

// Round 4
// 552.034 us; speedup vs baseline: 20.6532x; 1.2261x over previous
//
#include <hip/hip_runtime.h>
#include <hip/hip_bf16.h>
#include <cstddef>

#define B_   16
#define N_   1024
#define H_   2
#define D_   128
#define A_   256
#define FFN_ 1024
#define M_   (B_ * N_)   // 16384 rows
#define EPS_ 1e-5f
#define SPLIT 4
#define KT   32                    // keys per tile
#define TPC  (N_ / SPLIT / KT)     // tiles per chunk = 8
#define QKV_E ((size_t)B_ * H_ * N_ * D_)

typedef short  short8  __attribute__((ext_vector_type(8)));
typedef float  f32x16  __attribute__((ext_vector_type(16)));
typedef unsigned int uint;
typedef unsigned short ushort;

#define MFMA32(a, b, c) __builtin_amdgcn_mfma_f32_32x32x16_bf16(a, b, c, 0, 0, 0)

__device__ __forceinline__ uint f2b1(float x) {
    uint u = __float_as_uint(x);
    return (u + 0x7fffu + ((u >> 16) & 1u)) >> 16;
}
__device__ __forceinline__ uint f2b2(float lo, float hi) {
    return f2b1(lo) | (f2b1(hi) << 16);
}
__device__ __forceinline__ float b2f(ushort u) {
    return __uint_as_float(((uint)u) << 16);
}

// ---------------------------------------------------------------------------
// fp32 -> bf16 bulk convert (8 elems/thread)
// ---------------------------------------------------------------------------
__global__ __launch_bounds__(256) void f32_to_bf16_kernel(
    const float* __restrict__ in, ushort* __restrict__ out)
{
    const size_t i = ((size_t)blockIdx.x * 256 + threadIdx.x) * 8;
    float4 a = *(const float4*)(in + i);
    float4 b = *(const float4*)(in + i + 4);
    uint4 w = { f2b2(a.x, a.y), f2b2(a.z, a.w), f2b2(b.x, b.y), f2b2(b.z, b.w) };
    *(uint4*)(out + i) = w;
}

// ---------------------------------------------------------------------------
// Weight prep: W[K][N] fp32 -> Wt[N][K] bf16, blockIdx.z = layer (strided)
// ---------------------------------------------------------------------------
__global__ __launch_bounds__(256) void transpose_bf16_kernel(
    const float* __restrict__ W, ushort* __restrict__ Wt, int K, int N,
    size_t sstride, size_t dstride)
{
    __shared__ float tile[32][33];
    W  += (size_t)blockIdx.z * sstride;
    Wt += (size_t)blockIdx.z * dstride;
    const int n0 = blockIdx.x * 32, k0 = blockIdx.y * 32;
    const int tc = threadIdx.x & 31, tr = threadIdx.x >> 5;
#pragma unroll
    for (int it = 0; it < 4; ++it) {
        int r = it * 8 + tr;
        tile[r][tc] = W[(size_t)(k0 + r) * N + n0 + tc];
    }
    __syncthreads();
#pragma unroll
    for (int it = 0; it < 4; ++it) {
        int r = it * 8 + tr;
        Wt[(size_t)(n0 + r) * K + k0 + tc] = (ushort)f2b1(tile[tc][r]);
    }
}

// packed QKV transpose: z = layer*3 + sec
__global__ __launch_bounds__(256) void transpose_qkv_kernel(
    const float* __restrict__ Wq, const float* __restrict__ Wk,
    const float* __restrict__ Wv, ushort* __restrict__ dst)
{
    __shared__ float tile[32][33];
    const int layer = blockIdx.z / 3, sec = blockIdx.z % 3;
    const float* W = (sec == 0 ? Wq : sec == 1 ? Wk : Wv) + (size_t)layer * A_ * A_;
    ushort* out = dst + (size_t)layer * (3 * A_ * A_) + (size_t)sec * A_ * A_;
    const int n0 = blockIdx.x * 32, k0 = blockIdx.y * 32;
    const int tc = threadIdx.x & 31, tr = threadIdx.x >> 5;
#pragma unroll
    for (int it = 0; it < 4; ++it) {
        int r = it * 8 + tr;
        tile[r][tc] = W[(size_t)(k0 + r) * A_ + n0 + tc];
    }
    __syncthreads();
#pragma unroll
    for (int it = 0; it < 4; ++it) {
        int r = it * 8 + tr;
        out[(size_t)(n0 + r) * A_ + k0 + tc] = (ushort)f2b1(tile[tc][r]);
    }
}

// ---------------------------------------------------------------------------
// MFMA GEMM: out = epilogue(A[M,K](bf16) @ Wt^T + bias)
// modes: 1 = relu fp32 (ldc)   2 = relu bf16 (ldc)
//        5 = fused QKV: q heads / k heads / v transposed [bh][d][n]
// ---------------------------------------------------------------------------
__global__ __launch_bounds__(256) void gemm_mfma(
    const ushort* __restrict__ Asrc, const ushort* __restrict__ Wt,
    const float* __restrict__ bias, const float* __restrict__ biasK,
    const float* __restrict__ biasV, void* __restrict__ outp,
    int K, int ldc, int mode)
{
    __shared__ ushort sA[128 * 72];
    __shared__ ushort sB[128 * 72];

    const int tid = threadIdx.x;
    const int wid = tid >> 6, lane = tid & 63;
    const int c = lane & 31, g = lane >> 5;
    const int wr = wid >> 1, wc = wid & 1;
    const int m0 = blockIdx.x * 128;
    const int n0 = blockIdx.y * 128;

    f32x16 acc[2][2] = {};

    for (int k0 = 0; k0 < K; k0 += 64) {
        __syncthreads();
#pragma unroll
        for (int it = 0; it < 4; ++it) {
            int idx = it * 256 + tid, r = idx >> 3, cc = (idx & 7) * 8;
            *(uint4*)&sA[r * 72 + cc] =
                *(const uint4*)(Asrc + (size_t)(m0 + r) * K + k0 + cc);
        }
#pragma unroll
        for (int it = 0; it < 4; ++it) {
            int idx = it * 256 + tid, r = idx >> 3, cc = (idx & 7) * 8;
            *(uint4*)&sB[r * 72 + cc] =
                *(const uint4*)(Wt + (size_t)(n0 + r) * K + k0 + cc);
        }
        __syncthreads();
#pragma unroll
        for (int ks = 0; ks < 4; ++ks) {
            const int ko = ks * 16 + 8 * g;
            short8 a0 = *(const short8*)&sA[(wr * 64 + c) * 72 + ko];
            short8 a1 = *(const short8*)&sA[(wr * 64 + 32 + c) * 72 + ko];
            short8 b0 = *(const short8*)&sB[(wc * 64 + c) * 72 + ko];
            short8 b1 = *(const short8*)&sB[(wc * 64 + 32 + c) * 72 + ko];
            acc[0][0] = MFMA32(a0, b0, acc[0][0]);
            acc[0][1] = MFMA32(a0, b1, acc[0][1]);
            acc[1][0] = MFMA32(a1, b0, acc[1][0]);
            acc[1][1] = MFMA32(a1, b1, acc[1][1]);
        }
    }

    const int sec = n0 >> 8;  // for mode 5 (block-uniform)
    const float* bp = bias;
    int nw = n0;
    if (mode == 5) {
        bp = (sec == 0 ? bias : sec == 1 ? biasK : biasV);
        nw = n0 & 255;
    }
    const float bz[2] = { bp[nw + wc * 64 + c], bp[nw + wc * 64 + 32 + c] };

#pragma unroll
    for (int mr = 0; mr < 2; ++mr) {
#pragma unroll
        for (int ct = 0; ct < 2; ++ct) {
            const int colbase = n0 + wc * 64 + ct * 32 + c;
#pragma unroll
            for (int rg = 0; rg < 4; ++rg) {
                const int row = m0 + wr * 64 + mr * 32 + 8 * rg + 4 * g;
                float v0 = acc[mr][ct][4 * rg + 0] + bz[ct];
                float v1 = acc[mr][ct][4 * rg + 1] + bz[ct];
                float v2 = acc[mr][ct][4 * rg + 2] + bz[ct];
                float v3 = acc[mr][ct][4 * rg + 3] + bz[ct];
                if (mode == 1 || mode == 2) {
                    v0 = fmaxf(v0, 0.f); v1 = fmaxf(v1, 0.f);
                    v2 = fmaxf(v2, 0.f); v3 = fmaxf(v3, 0.f);
                }
                if (mode == 1) {
                    float* o = (float*)outp;
                    o[(size_t)(row + 0) * ldc + colbase] = v0;
                    o[(size_t)(row + 1) * ldc + colbase] = v1;
                    o[(size_t)(row + 2) * ldc + colbase] = v2;
                    o[(size_t)(row + 3) * ldc + colbase] = v3;
                } else if (mode == 2) {
                    ushort* o = (ushort*)outp;
                    o[(size_t)(row + 0) * ldc + colbase] = (ushort)f2b1(v0);
                    o[(size_t)(row + 1) * ldc + colbase] = (ushort)f2b1(v1);
                    o[(size_t)(row + 2) * ldc + colbase] = (ushort)f2b1(v2);
                    o[(size_t)(row + 3) * ldc + colbase] = (ushort)f2b1(v3);
                } else {  // mode 5
                    const int cw = colbase & 255;
                    const int hh = cw >> 7, dd = cw & (D_ - 1);
                    if (sec < 2) {
                        ushort* o = (ushort*)outp + (size_t)sec * QKV_E;
#pragma unroll
                        for (int r2 = 0; r2 < 4; ++r2) {
                            int rw = row + r2;
                            int bb = rw >> 10, np = rw & (N_ - 1);
                            float vv = (r2 == 0 ? v0 : r2 == 1 ? v1 : r2 == 2 ? v2 : v3);
                            o[(((size_t)(bb * H_ + hh) * N_ + np) * D_) + dd] = (ushort)f2b1(vv);
                        }
                    } else {
                        ushort* o = (ushort*)outp + 2 * QKV_E;
                        const int bb = row >> 10, np = row & (N_ - 1);
                        uint2 w = { f2b2(v0, v1), f2b2(v2, v3) };
                        *(uint2*)(o + ((size_t)(bb * H_ + hh) * D_ + dd) * N_ + np) = w;
                    }
                }
            }
        }
    }
}

// ---------------------------------------------------------------------------
// Flash attention with grid split-KV + XCD-swizzled 1D grid.
// block = 128 thr (2 waves x 32 queries), KV chunk = 256 keys, tile = 32 keys.
// Partial O written via LDS transpose -> fully coalesced bf16 [row][d].
// ---------------------------------------------------------------------------
#define OPITCH 132   // bf16 elems per q-row in sO (66 words: bank-stride 2)

__global__ __launch_bounds__(128) void attn_kernel(
    const ushort* __restrict__ qg, const ushort* __restrict__ kg,
    const ushort* __restrict__ vtg, ushort* __restrict__ po,
    float* __restrict__ pm, float* __restrict__ pl)
{
    __shared__ ushort smem[9472];        // 18944 B
    ushort* sK  = smem;                  // [32 keys][136]
    ushort* sVt = smem + KT * 136;       // [128 d][40]
    ushort* sO  = smem;                  // epilogue overlay [64 q][OPITCH]

    const int tid = threadIdx.x;
    const int w = tid >> 6, lane = tid & 63;
    const int c = lane & 31, g = lane >> 5;

    // XCD-aware decomposition: keep all 16 q-tiles of one (bh,z) on one XCD
    const int flat = blockIdx.x;          // 0..2047
    const int xcd  = flat & 7;
    const int ii   = flat >> 3;           // 0..255
    const int pair = xcd * 16 + (ii & 15);// 0..127 = (z,bh)
    const int qt   = ii >> 4;             // 0..15
    const int bh   = pair & 31;
    const int z    = pair >> 5;

    const int q0 = qt * 64 + w * 32;
    const size_t bhoff = (size_t)bh * (N_ * D_);
    const int kt0 = z * (N_ / SPLIT);
    const float scale2 = 0.08838834764831845f * 1.44269504f;  // /sqrt(128)*log2e
    const float THR = 11.5f;

    short8 qf[8];
    const ushort* qrow = qg + bhoff + (size_t)(q0 + c) * D_;
#pragma unroll
    for (int ks = 0; ks < 8; ++ks)
        qf[ks] = *(const short8*)(qrow + ks * 16 + 8 * g);

    f32x16 oacc[4] = {};
    float m = -1e30f, l = 0.f;

    uint4 kreg[4], vreg[4];
    auto loadK = [&](int t) {
        const ushort* src = kg + bhoff + (size_t)(kt0 + t * KT) * D_;
#pragma unroll
        for (int it = 0; it < 4; ++it) {
            int idx = it * 128 + tid;
            kreg[it] = *(const uint4*)(src + (size_t)(idx >> 4) * D_ + (idx & 15) * 8);
        }
    };
    auto loadV = [&](int t) {
        const ushort* src = vtg + bhoff + kt0 + t * KT;
#pragma unroll
        for (int it = 0; it < 4; ++it) {
            int idx = it * 128 + tid;
            vreg[it] = *(const uint4*)(src + (size_t)(idx >> 2) * N_ + (idx & 3) * 8);
        }
    };
    auto writeLDS = [&]() {
#pragma unroll
        for (int it = 0; it < 4; ++it) {
            int idx = it * 128 + tid;
            *(uint4*)&sK[(idx >> 4) * 136 + (idx & 15) * 8] = kreg[it];
        }
#pragma unroll
        for (int it = 0; it < 4; ++it) {
            int idx = it * 128 + tid;
            *(uint4*)&sVt[(idx >> 2) * 40 + (idx & 3) * 8] = vreg[it];
        }
    };

    loadK(0); loadV(0);
    writeLDS();
    __syncthreads();

    for (int t = 0; t < TPC; ++t) {
        if (t + 1 < TPC) { loadK(t + 1); loadV(t + 1); }

        // ---- S^T = K · Q^T ----
        f32x16 sacc = {};
#pragma unroll
        for (int ks = 0; ks < 8; ++ks) {
            short8 a = *(const short8*)&sK[c * 136 + ks * 16 + 8 * g];
            sacc = MFMA32(a, qf[ks], sacc);
        }

        // ---- online softmax (exp2 domain, defer-max) ----
        float p[16];
        float tmax = -1e30f;
#pragma unroll
        for (int r = 0; r < 16; ++r) {
            float s = sacc[r] * scale2;
            p[r] = s;
            tmax = fmaxf(tmax, s);
        }
        tmax = fmaxf(tmax, __shfl_xor(tmax, 32, 64));
        if (!__all(tmax - m <= THR)) {
            const float mnew = fmaxf(m, tmax);
            const float corr = exp2f(m - mnew);
#pragma unroll
            for (int dt = 0; dt < 4; ++dt)
#pragma unroll
                for (int r = 0; r < 16; ++r) oacc[dt][r] *= corr;
            l *= corr;
            m = mnew;
        }
        float tsum = 0.f;
#pragma unroll
        for (int r = 0; r < 16; ++r) {
            p[r] = exp2f(p[r] - m);
            tsum += p[r];
        }
        tsum += __shfl_xor(tsum, 32, 64);
        l += tsum;

        uint pk[8];
#pragma unroll
        for (int pp = 0; pp < 8; ++pp)
            pk[pp] = f2b2(p[2 * pp], p[2 * pp + 1]);

        uint v0 = g ? pk[0] : pk[2];
        uint v1 = g ? pk[1] : pk[3];
        uint v2 = g ? pk[4] : pk[6];
        uint v3 = g ? pk[5] : pk[7];
        uint r0 = (uint)__shfl_xor((int)v0, 32, 64);
        uint r1 = (uint)__shfl_xor((int)v1, 32, 64);
        uint r2 = (uint)__shfl_xor((int)v2, 32, 64);
        uint r3 = (uint)__shfl_xor((int)v3, 32, 64);

        // ---- O^T += V^T · P^T ----
#pragma unroll
        for (int kb = 0; kb < 2; ++kb) {
            union { uint u[4]; short8 s; } pf;
            if (kb == 0) {
                pf.u[0] = g ? r0 : pk[0];
                pf.u[1] = g ? r1 : pk[1];
                pf.u[2] = g ? pk[2] : r0;
                pf.u[3] = g ? pk[3] : r1;
            } else {
                pf.u[0] = g ? r2 : pk[4];
                pf.u[1] = g ? r3 : pk[5];
                pf.u[2] = g ? pk[6] : r2;
                pf.u[3] = g ? pk[7] : r3;
            }
#pragma unroll
            for (int dt = 0; dt < 4; ++dt) {
                short8 a = *(const short8*)&sVt[(dt * 32 + c) * 40 + kb * 16 + 8 * g];
                oacc[dt] = MFMA32(a, pf.s, oacc[dt]);
            }
        }

        __syncthreads();
        if (t + 1 < TPC) { writeLDS(); __syncthreads(); }
    }

    // ---- epilogue: LDS transpose -> coalesced bf16 partial-O write ----
    if (lane < 32) {
        pm[(size_t)(z * 32 + bh) * N_ + q0 + c] = m;
        pl[(size_t)(z * 32 + bh) * N_ + q0 + c] = l;
    }
    {
        const int qrl = w * 32 + c;
#pragma unroll
        for (int dt = 0; dt < 4; ++dt)
#pragma unroll
            for (int rg = 0; rg < 4; ++rg) {
                int d = dt * 32 + 8 * rg + 4 * g;
                uint2 pv = { f2b2(oacc[dt][4 * rg + 0], oacc[dt][4 * rg + 1]),
                             f2b2(oacc[dt][4 * rg + 2], oacc[dt][4 * rg + 3]) };
                *(uint2*)&sO[qrl * OPITCH + d] = pv;
            }
    }
    __syncthreads();
    {
        const size_t pbase = ((size_t)(z * 32 + bh) * N_ + qt * 64) * D_;
#pragma unroll
        for (int it = 0; it < 16; ++it) {
            int idx = it * 128 + tid;            // 0..2047 (8B granules)
            int r = idx >> 5, dgr = (idx & 31) * 4;
            uint2 v = *(const uint2*)&sO[r * OPITCH + dgr];
            *(uint2*)(po + pbase + (size_t)r * D_ + dgr) = v;
        }
    }
}

// ---------------------------------------------------------------------------
// Combine split-KV partials -> bf16 [b][n][A] (feeds FFN1 directly)
// ---------------------------------------------------------------------------
__global__ __launch_bounds__(256) void combine_kernel(
    const ushort* __restrict__ po, const float* __restrict__ pm,
    const float* __restrict__ pl, ushort* __restrict__ out)
{
    const int idx = blockIdx.x * 256 + threadIdx.x;
    const int row = idx >> 7, d = idx & 127;
    const int R = B_ * H_ * N_;  // 32768

    float ms[SPLIT];
    float M = -1e30f;
#pragma unroll
    for (int s = 0; s < SPLIT; ++s) {
        ms[s] = pm[(size_t)s * R + row];
        M = fmaxf(M, ms[s]);
    }
    float L = 0.f, acc = 0.f;
#pragma unroll
    for (int s = 0; s < SPLIT; ++s) {
        float wgt = exp2f(ms[s] - M);
        L += pl[(size_t)s * R + row] * wgt;
        acc += b2f(po[((size_t)s * R + row) * D_ + d]) * wgt;
    }
    const int bh = row >> 10, n = row & (N_ - 1);
    const int bb = bh >> 1, hh = bh & 1;
    out[((size_t)(bb * N_ + n)) * A_ + hh * D_ + d] = (ushort)f2b1(acc / L);
}

// ---------------------------------------------------------------------------
// step = LayerNorm(roll + prev)*g+b  -> fp32 (residual) + bf16 (GEMM A)
// ---------------------------------------------------------------------------
__global__ __launch_bounds__(256) void add_ln_kernel(
    const float* __restrict__ roll, const float* __restrict__ prev,
    const float* __restrict__ g, const float* __restrict__ bta,
    float* __restrict__ out, ushort* __restrict__ outb)
{
    const int row = blockIdx.x, tid = threadIdx.x;
    float v = roll[(size_t)row * A_ + tid] + prev[(size_t)row * A_ + tid];
    float s = v, s2 = v * v;
#pragma unroll
    for (int o = 32; o > 0; o >>= 1) {
        s  += __shfl_down(s, o, 64);
        s2 += __shfl_down(s2, o, 64);
    }
    __shared__ float ps[4], ps2[4];
    __shared__ float mu_s, rsig_s;
    const int wid = tid >> 6, lane = tid & 63;
    if (lane == 0) { ps[wid] = s; ps2[wid] = s2; }
    __syncthreads();
    if (tid == 0) {
        float S  = ps[0] + ps[1] + ps[2] + ps[3];
        float S2 = ps2[0] + ps2[1] + ps2[2] + ps2[3];
        float mu = S / A_;
        float var = S2 / A_ - mu * mu;
        mu_s = mu;
        rsig_s = rsqrtf(var + EPS_);
    }
    __syncthreads();
    float y = (v - mu_s) * rsig_s * g[tid] + bta[tid];
    out[(size_t)row * A_ + tid] = y;
    outb[(size_t)row * A_ + tid] = (ushort)f2b1(y);
}

// ---------------------------------------------------------------------------
__global__ __launch_bounds__(256) void pool_kernel(
    const float* __restrict__ ent, float* __restrict__ part)
{
    const int b = blockIdx.x, s = blockIdx.y, a = threadIdx.x;
    float acc = 0.f;
    for (int n = s * 32; n < s * 32 + 32; ++n)
        acc += ent[((size_t)b * N_ + n) * A_ + a];
    part[((size_t)b * 32 + s) * A_ + a] = acc;
}

__global__ __launch_bounds__(256) void final_kernel(
    const float* __restrict__ part, const float* __restrict__ We,
    const float* __restrict__ be, float* __restrict__ out)
{
    __shared__ float sp[A_];
    const int b = blockIdx.x, tid = threadIdx.x;
    float s = 0.f;
    for (int j = 0; j < 32; ++j) s += part[((size_t)b * 32 + j) * A_ + tid];
    sp[tid] = s * (1.0f / N_);
    __syncthreads();
    float acc = be[tid];
    for (int kk = 0; kk < A_; ++kk) acc += sp[kk] * We[(size_t)kk * A_ + tid];
    out[b * A_ + tid] = fmaxf(acc, 0.f);
}

// ---------------------------------------------------------------------------
extern "C" void kernel_launch(void* const* d_in, const int* in_sizes, int n_in,
                              void* d_out, int out_size, void* d_ws, size_t ws_size,
                              hipStream_t stream)
{
    const float* X    = (const float*)d_in[0];
    const float* Wq   = (const float*)d_in[1];
    const float* bq   = (const float*)d_in[2];
    const float* Wk   = (const float*)d_in[3];
    const float* bk   = (const float*)d_in[4];
    const float* Wv   = (const float*)d_in[5];
    const float* bv   = (const float*)d_in[6];
    const float* W1   = (const float*)d_in[7];
    const float* b1   = (const float*)d_in[8];
    const float* W2   = (const float*)d_in[9];
    const float* b2   = (const float*)d_in[10];
    const float* ln_g = (const float*)d_in[11];
    const float* ln_b = (const float*)d_in[12];
    const float* Wc   = (const float*)d_in[13];
    const float* bc   = (const float*)d_in[14];
    const float* We   = (const float*)d_in[15];
    const float* be   = (const float*)d_in[16];

    // ---- workspace layout (~107 MB) ----
    char* base = (char*)d_ws;
    ushort* qb     = (ushort*)base;  base += QKV_E * 2;   // q; attnb alias
    /* kb */                         base += QKV_E * 2;
    /* vt */                         base += QKV_E * 2;
    ushort* hbuf   = (ushort*)base;  base += (size_t)M_ * FFN_ * 2;  // aliases po/ent
    float*  attn   = (float*)base;   base += (size_t)M_ * A_ * 4;    // roll fp32
    float*  step   = (float*)base;   base += (size_t)M_ * A_ * 4;
    ushort* stepb  = (ushort*)base;  base += (size_t)M_ * A_ * 2;
    ushort* wqkv_t = (ushort*)base;  base += (size_t)3 * 3 * A_ * A_ * 2;
    ushort* w1_t   = (ushort*)base;  base += (size_t)3 * A_ * FFN_ * 2;
    ushort* w2_t   = (ushort*)base;  base += (size_t)3 * FFN_ * A_ * 2;
    ushort* wc_t   = (ushort*)base;  base += (size_t)A_ * A_ * 2;
    float*  part   = (float*)base;   base += (size_t)B_ * 32 * A_ * 4;
    float*  pm     = (float*)base;   base += (size_t)SPLIT * B_ * H_ * N_ * 4;
    float*  pl     = (float*)base;   base += (size_t)SPLIT * B_ * H_ * N_ * 4;
    ushort* kbuf   = qb + QKV_E;
    ushort* vtbuf  = qb + 2 * QKV_E;
    ushort* po     = hbuf;           // partial O: dead before FFN1 writes hbuf
    ushort* attnb  = qb;             // combine out: q dead after attn_kernel
    float*  ent    = (float*)hbuf;   // head output reuses hbuf

    // ---- weight/input prep ----
    transpose_qkv_kernel<<<dim3(8, 8, 9), 256, 0, stream>>>(Wq, Wk, Wv, wqkv_t);
    transpose_bf16_kernel<<<dim3(FFN_/32, A_/32, 3), 256, 0, stream>>>(
        W1, w1_t, A_, FFN_, (size_t)A_ * FFN_, (size_t)A_ * FFN_);
    transpose_bf16_kernel<<<dim3(A_/32, FFN_/32, 3), 256, 0, stream>>>(
        W2, w2_t, FFN_, A_, (size_t)FFN_ * A_, (size_t)FFN_ * A_);
    transpose_bf16_kernel<<<dim3(A_/32, A_/32, 1), 256, 0, stream>>>(
        Wc, wc_t, A_, A_, 0, 0);
    f32_to_bf16_kernel<<<(M_ * A_) / (256 * 8), 256, 0, stream>>>(X, stepb);

    const float* cur = X;   // fp32 residual input
    for (int i = 0; i < 3; ++i) {
        // fused QKV projection (A = stepb bf16)
        gemm_mfma<<<dim3(M_/128, 6), 256, 0, stream>>>(
            stepb, wqkv_t + (size_t)i * 3 * A_ * A_,
            bq + i * A_, bk + i * A_, bv + i * A_, qb, A_, 0, 5);

        attn_kernel<<<16 * SPLIT * B_ * H_, 128, 0, stream>>>(
            qb, kbuf, vtbuf, po, pm, pl);
        combine_kernel<<<(B_*H_*N_*D_)/256, 256, 0, stream>>>(po, pm, pl, attnb);

        gemm_mfma<<<dim3(M_/128, FFN_/128), 256, 0, stream>>>(
            attnb, w1_t + (size_t)i * A_ * FFN_, b1 + i * FFN_, nullptr, nullptr,
            hbuf, A_, FFN_, 2);
        gemm_mfma<<<dim3(M_/128, A_/128), 256, 0, stream>>>(
            hbuf, w2_t + (size_t)i * FFN_ * A_, b2 + i * A_, nullptr, nullptr,
            attn, FFN_, A_, 1);

        // writes step (fp32 residual) + stepb (bf16 A for next QKV / head)
        add_ln_kernel<<<M_, 256, 0, stream>>>(attn, cur, ln_g, ln_b, step, stepb);
        cur = step;
    }

    // head
    gemm_mfma<<<dim3(M_/128, A_/128), 256, 0, stream>>>(
        stepb, wc_t, bc, nullptr, nullptr, ent, A_, A_, 1);
    pool_kernel<<<dim3(B_, 32), 256, 0, stream>>>(ent, part);
    final_kernel<<<B_, 256, 0, stream>>>(part, We, be, (float*)d_out);
}